// Round 3
// baseline (466.572 us; speedup 1.0000x reference)
//
#include <hip/hip_runtime.h>

// NLQR: NB=1024, T=128, NS=12, NC=4, N=16.
// Round 3: critical-path cuts on the round-2 structure (64 lanes/batch,
// 1 wave/block, zero barriers, wave-synchronous LDS):
//  - SPD 2x2-block Schur inverse for Quu (~55 ops vs ~220 cofactor)
//  - double-buffered FT staging (next iter's F^T written mid-body)
//  - publish->read->inverse overlap choreography
//  - forward pass: ds_bpermute x-broadcast (no LDS round trip) + 2-deep prefetch

#define NBQ 1024
#define TT  128

__device__ __forceinline__ float dotf4(float4 a, float4 b) {
  return a.x*b.x + a.y*b.y + a.z*b.z + a.w*b.w;
}
__device__ __forceinline__ float dpp_qx1(float x) {  // quad_perm [1,0,3,2]
  return __int_as_float(__builtin_amdgcn_mov_dpp(__float_as_int(x), 0xB1, 0xF, 0xF, true));
}
__device__ __forceinline__ float dpp_qx2(float x) {  // quad_perm [2,3,0,1]
  return __int_as_float(__builtin_amdgcn_mov_dpp(__float_as_int(x), 0x4E, 0xF, 0xF, true));
}

__global__ __launch_bounds__(64) void lqr_fused(
    const float* __restrict__ Q, const float* __restrict__ p,
    const float* __restrict__ A, const float* __restrict__ Bm,
    const float* __restrict__ cu, const float* __restrict__ xinit,
    float* __restrict__ out)
{
  // LDS carve (dwords), 16B-aligned sub-arrays. 5.5 KB/block.
  __shared__ __align__(16) float lds[1376];
  float* FT0 = lds;        // [16][12] F^T buffer 0
  float* FT1 = lds + 192;  // [16][12] F^T buffer 1
  float* Vs  = lds + 384;  // [12][12] V row-major
  float* vvS = lds + 528;  // [12]
  float* msh = lds + 544;  // [12][16] m = V*F
  float* UxS = lds + 736;  // [4][16]  Qt rows 12..15 (Qux | Quu)
  float* XuS = lds + 800;  // [12][4]  Qxu
  float* quS = lds + 848;  // [4]
  float* uL  = lds + 864;  // [128][4] u stash for forward

  const int l  = threadIdx.x;
  const int j  = l & 15;
  const int r  = l >> 4;
  const int i4 = l >> 2;
  const int q4 = l & 3;
  const int c0 = q4 << 2;
  const long b = blockIdx.x;

  float* xs_out = out;
  float* us_out = out + (long)NBQ*TT*12;
  float* c_out  = out + (long)NBQ*TT*12 + (long)NBQ*TT*4;

  // zero-init V, v
  if (i4 < 12 && q4 < 3) *(float4*)(Vs + i4*12 + c0) = make_float4(0.f,0.f,0.f,0.f);
  if (l < 12) vvS[l] = 0.f;

  // Static staging indices: lanes 0..35 cover A (flat=4l+e, k=flat/12, n=flat%12),
  // lanes 36..47 cover B.
  const int aoff = 4*min(l,35);
  const int boff = 4*min(max(l-36,0),11);
  int fta[4];
  #pragma unroll
  for (int e=0;e<4;++e){ int flat=4*l+e; int k=(flat*171)>>11; int n=flat-12*k; fta[e]=n*12+k; }

  long bt = b*TT + (TT-1);
  float4 qv  = *(const float4*)(Q  + bt*256 + 4*l);
  float4 av  = *(const float4*)(A  + bt*144 + aoff);
  float4 bv  = *(const float4*)(Bm + bt*48  + boff);
  float  pv  = p[bt*16 + j];
  float  cuv = cu[bt*4 + q4];

  // prologue: stage F^T for t=TT-1 into buf[1] (127&1 == 1)
  if (l < 36) {
    FT1[fta[0]] = av.x; FT1[fta[1]] = av.y; FT1[fta[2]] = av.z; FT1[fta[3]] = av.w;
  } else if (l < 48) {
    const int kk = l - 36;
    FT1[12*12+kk] = bv.x; FT1[13*12+kk] = bv.y; FT1[14*12+kk] = bv.z; FT1[15*12+kk] = bv.w;
  }

  // ---------------- backward Riccati scan ----------------
  #pragma unroll 1
  for (int t = TT-1; t >= 0; --t) {
    const long btn = bt - (t > 0 ? 1 : 0);
    // prefetch t-1 (lands during this body)
    float4 qn  = *(const float4*)(Q  + btn*256 + 4*l);
    float4 an  = *(const float4*)(A  + btn*144 + aoff);
    float4 bn  = *(const float4*)(Bm + btn*48  + boff);
    float  pn  = p[btn*16 + j];
    float  cun = cu[btn*4 + q4];

    float* FTc = (t & 1) ? FT1 : FT0;   // current (already staged)
    float* FTn = (t & 1) ? FT0 : FT1;   // next (staged mid-body below)

    // issue all top-of-iter LDS reads immediately (FTc is ready)
    const float4* fj4 = (const float4*)(FTc + j*12);
    float4 f0 = fj4[0], f1 = fj4[1], f2 = fj4[2];
    const float4* gi4 = (const float4*)(FTc + i4*12);
    float4 g0 = gi4[0], g1 = gi4[1], g2 = gi4[2];
    const float4* vv4 = (const float4*)vvS;
    float4 w0 = vv4[0], w1 = vv4[1], w2 = vv4[2];
    const float4* vr0 = (const float4*)(Vs + (3*r+0)*12);
    const float4* vr1 = (const float4*)(Vs + (3*r+1)*12);
    const float4* vr2 = (const float4*)(Vs + (3*r+2)*12);
    float4 a0=vr0[0], a1=vr0[1], a2=vr0[2];
    float4 b0=vr1[0], b1=vr1[1], b2=vr1[2];
    float4 c0v=vr2[0], c1=vr2[1], c2=vr2[2];

    // m[3r..3r+2][j] = V rows . F col j
    float m0 = dotf4(a0,f0) + dotf4(a1,f1) + dotf4(a2,f2);
    float m1 = dotf4(b0,f0) + dotf4(b1,f1) + dotf4(b2,f2);
    float m2 = dotf4(c0v,f0) + dotf4(c1,f1) + dotf4(c2,f2);
    msh[(3*r+0)*16 + j] = m0;
    msh[(3*r+1)*16 + j] = m1;
    msh[(3*r+2)*16 + j] = m2;

    // qtv (independent of msh) fills the msh write->read latency
    float qtv = pv + dotf4(w0,f0) + dotf4(w1,f1) + dotf4(w2,f2);

    // Qt[i4][c0..c0+3] = Q + sum_k FT[i4][k] * m[k][c0..c0+3]
    float gk[12] = {g0.x,g0.y,g0.z,g0.w, g1.x,g1.y,g1.z,g1.w, g2.x,g2.y,g2.z,g2.w};
    float4 qt4 = qv;
    #pragma unroll
    for (int k2 = 0; k2 < 12; ++k2) {
      float4 mk = *(const float4*)(msh + k2*16 + c0);
      qt4.x += gk[k2]*mk.x; qt4.y += gk[k2]*mk.y;
      qt4.z += gk[k2]*mk.z; qt4.w += gk[k2]*mk.w;
    }

    // publish Qux|Quu rows, Qxu rows, qu
    if (l >= 48)            *(float4*)(UxS + (i4-12)*16 + c0) = qt4;
    if (q4 == 3 && i4 < 12) *(float4*)(XuS + i4*4) = qt4;
    if (l >= 12 && l < 16)  quS[l-12] = qtv;

    // issue ALL dependent reads now; inverse below only waits on mm
    float mm[16];
    #pragma unroll
    for (int c = 0; c < 4; ++c) {
      float4 qq = *(const float4*)(UxS + c*16 + 12);
      mm[c*4+0]=qq.x; mm[c*4+1]=qq.y; mm[c*4+2]=qq.z; mm[c*4+3]=qq.w;
    }
    float4 quv = *(const float4*)quS;
    float4 ux0 = *(const float4*)(UxS + 0*16 + c0);
    float4 ux1 = *(const float4*)(UxS + 1*16 + c0);
    float4 ux2 = *(const float4*)(UxS + 2*16 + c0);
    float4 ux3 = *(const float4*)(UxS + 3*16 + c0);
    const int i4c12 = min(i4, 11);
    float4 xr = *(const float4*)(XuS + i4c12*4);
    const int jc12 = min(j, 11);
    float4 xj = *(const float4*)(XuS + jc12*4);

    // SPD 2x2-block Schur inverse of Quu (symmetric, ~55 ops)
    float rdp = 1.0f/(mm[0]*mm[5] - mm[1]*mm[1]);
    float pi00 = mm[5]*rdp, pi01 = -mm[1]*rdp, pi11 = mm[0]*rdp;
    float w00 = pi00*mm[2] + pi01*mm[6];
    float w01 = pi00*mm[3] + pi01*mm[7];
    float w10 = pi01*mm[2] + pi11*mm[6];
    float w11 = pi01*mm[3] + pi11*mm[7];
    float t00 = mm[10] - (mm[2]*w00 + mm[6]*w10);
    float t01 = mm[11] - (mm[2]*w01 + mm[6]*w11);
    float t11 = mm[15] - (mm[3]*w01 + mm[7]*w11);
    float rdt = 1.0f/(t00*t11 - t01*t01);
    float ti00 = t11*rdt, ti01 = -t01*rdt, ti11 = t00*rdt;
    float u00 = -(w00*ti00 + w01*ti01);
    float u01 = -(w00*ti01 + w01*ti11);
    float u10 = -(w10*ti00 + w11*ti01);
    float u11 = -(w10*ti01 + w11*ti11);
    float i00 = pi00 - (u00*w00 + u01*w01);
    float i01 = pi01 - (u00*w10 + u01*w11);
    float i11 = pi11 - (u10*w10 + u11*w11);
    float inv[16] = { i00, i01, u00, u01,
                      i01, i11, u10, u11,
                      u00, u10, ti00, ti01,
                      u01, u11, ti01, ti11 };

    float kt0 = -(inv[0] *quv.x + inv[1] *quv.y + inv[2] *quv.z + inv[3] *quv.w);
    float kt1 = -(inv[4] *quv.x + inv[5] *quv.y + inv[6] *quv.z + inv[7] *quv.w);
    float kt2 = -(inv[8] *quv.x + inv[9] *quv.y + inv[10]*quv.z + inv[11]*quv.w);
    float kt3 = -(inv[12]*quv.x + inv[13]*quv.y + inv[14]*quv.z + inv[15]*quv.w);

    float4 kc[4];
    #pragma unroll
    for (int c = 0; c < 4; ++c) {
      kc[c].x = -(inv[c*4+0]*ux0.x + inv[c*4+1]*ux1.x + inv[c*4+2]*ux2.x + inv[c*4+3]*ux3.x);
      kc[c].y = -(inv[c*4+0]*ux0.y + inv[c*4+1]*ux1.y + inv[c*4+2]*ux2.y + inv[c*4+3]*ux3.y);
      kc[c].z = -(inv[c*4+0]*ux0.z + inv[c*4+1]*ux1.z + inv[c*4+2]*ux2.z + inv[c*4+3]*ux3.z);
      kc[c].w = -(inv[c*4+0]*ux0.w + inv[c*4+1]*ux1.w + inv[c*4+2]*ux2.w + inv[c*4+3]*ux3.w);
    }

    // stage NEXT iteration's F^T here (an/bn have landed; buries write latency)
    if (l < 36) {
      FTn[fta[0]] = an.x; FTn[fta[1]] = an.y; FTn[fta[2]] = an.z; FTn[fta[3]] = an.w;
    } else if (l < 48) {
      const int kk = l - 36;
      FTn[12*12+kk] = bn.x; FTn[13*12+kk] = bn.y; FTn[14*12+kk] = bn.z; FTn[15*12+kk] = bn.w;
    }

    // Vn[i4][c0..c0+3] = Qt + Qxu row . K cols
    if (i4 < 12) {
      float4 vn4;
      vn4.x = qt4.x + xr.x*kc[0].x + xr.y*kc[1].x + xr.z*kc[2].x + xr.w*kc[3].x;
      vn4.y = qt4.y + xr.x*kc[0].y + xr.y*kc[1].y + xr.z*kc[2].y + xr.w*kc[3].y;
      vn4.z = qt4.z + xr.x*kc[0].z + xr.y*kc[1].z + xr.z*kc[2].z + xr.w*kc[3].z;
      vn4.w = qt4.w + xr.x*kc[0].w + xr.y*kc[1].w + xr.z*kc[2].w + xr.w*kc[3].w;
      if (q4 < 3) *(float4*)(Vs + i4*12 + c0) = vn4;
    }
    if (l < 12)
      vvS[l] = qtv + xj.x*kt0 + xj.y*kt1 + xj.z*kt2 + xj.w*kt3;

    // u_t = cu_t + kt
    float uv = cuv + ((q4==0)?kt0:(q4==1)?kt1:(q4==2)?kt2:kt3);
    if (l < 4) { us_out[bt*4 + l] = uv; uL[t*4 + l] = uv; }

    qv = qn; av = an; bv = bn; pv = pn; cuv = cun; bt = btn;
  }

  // ---------------- forward rollout + cost ----------------
  const int i4c = min(i4, 11);
  const int sl0 = (c0+0)<<2, sl1 = (c0+1)<<2, sl2 = (c0+2)<<2, sl3 = (c0+3)<<2;
  float s = xinit[b*12 + i4c];          // lane's row value (valid i4<12)
  float cacc = 0.f;

  const long bt0 = b*TT;
  // 2-deep prefetch: slots A (t), B (t+1)
  float4 qfA = *(const float4*)(Q + bt0*256 + 4*l);
  float4 ffA = (q4 < 3) ? *(const float4*)(A  + bt0*144 + i4c*12 + c0)
                        : *(const float4*)(Bm + bt0*48  + i4c*4);
  float  pfA = p[bt0*16 + i4];
  float4 qfB = *(const float4*)(Q + (bt0+1)*256 + 4*l);
  float4 ffB = (q4 < 3) ? *(const float4*)(A  + (bt0+1)*144 + i4c*12 + c0)
                        : *(const float4*)(Bm + (bt0+1)*48  + i4c*4);
  float  pfB = p[(bt0+1)*16 + i4];

  #pragma unroll 1
  for (int t = 0; t < TT; ++t) {
    const long btp = bt0 + min(t+2, TT-1);
    float4 qfC = *(const float4*)(Q + btp*256 + 4*l);
    float4 ffC = (q4 < 3) ? *(const float4*)(A  + btp*144 + i4c*12 + c0)
                          : *(const float4*)(Bm + btp*48  + i4c*4);
    float  pfC = p[btp*16 + i4];

    float4 u4 = *(const float4*)(uL + t*4);   // broadcast read

    // xuq = x[c0..c0+3] gathered straight from registers (q4<3), else u
    float4 xg;
    xg.x = __shfl(s, sl0, 64); xg.y = __shfl(s, sl1, 64);
    xg.z = __shfl(s, sl2, 64); xg.w = __shfl(s, sl3, 64);
    float4 xuq = (q4 < 3) ? xg : u4;
    float xui = (i4 < 12) ? s
              : (i4 == 12) ? u4.x : (i4 == 13) ? u4.y : (i4 == 14) ? u4.z : u4.w;

    if (q4 == 0 && i4 < 12) xs_out[(bt0+t)*12 + i4] = s;   // x_t (pre-update)

    // cost partials: 0.5 xu^T Q xu (+ xu.p on q4==0 lanes)
    cacc += 0.5f * xui * dotf4(qfA, xuq);
    if (q4 == 0) cacc += xui * pfA;

    // x' rows: quad partial + DPP quad reduction
    float zx = dotf4(ffA, xuq);
    zx += dpp_qx1(zx);
    zx += dpp_qx2(zx);
    s = zx;

    qfA = qfB; ffA = ffB; pfA = pfB;
    qfB = qfC; ffB = ffC; pfB = pfC;
  }

  // final 64-lane cost reduction
  cacc += __shfl_xor(cacc, 32, 64);
  cacc += __shfl_xor(cacc, 16, 64);
  cacc += __shfl_xor(cacc, 8, 64);
  cacc += __shfl_xor(cacc, 4, 64);
  cacc += dpp_qx2(cacc);
  cacc += dpp_qx1(cacc);
  if (l == 0) c_out[b] = cacc;
}

extern "C" void kernel_launch(void* const* d_in, const int* in_sizes, int n_in,
                              void* d_out, int out_size, void* d_ws, size_t ws_size,
                              hipStream_t stream) {
  const float* xinit = (const float*)d_in[0];
  // d_in[1] = current_x (unused by reference), d_in[7] = time (unused)
  const float* cu = (const float*)d_in[2];
  const float* Q  = (const float*)d_in[3];
  const float* p  = (const float*)d_in[4];
  const float* A  = (const float*)d_in[5];
  const float* Bm = (const float*)d_in[6];
  float* out = (float*)d_out;

  lqr_fused<<<dim3(NBQ), dim3(64), 0, stream>>>(Q, p, A, Bm, cu, xinit, out);
}

// Round 4
// 398.233 us; speedup vs baseline: 1.1716x; 1.1716x over previous
//
#include <hip/hip_runtime.h>

// NLQR: NB=1024, T=128, NS=12, NC=4, N=16.
// Round 4: same algebra/body as round 3 (validated), but 4-deep global
// prefetch pipeline (backward unrolled x4 with register slot rotation).
// Theory: effective memory latency under 1024 concurrent strided streams
// is ~4000 cyc; 1-deep prefetch pinned the loop at P ~= latency. With
// 4-deep slots every load has ~3.5 bodies of slack.

#define NBQ 1024
#define TT  128

__device__ __forceinline__ float dotf4(float4 a, float4 b) {
  return a.x*b.x + a.y*b.y + a.z*b.z + a.w*b.w;
}
__device__ __forceinline__ float dpp_qx1(float x) {  // quad_perm [1,0,3,2]
  return __int_as_float(__builtin_amdgcn_mov_dpp(__float_as_int(x), 0xB1, 0xF, 0xF, true));
}
__device__ __forceinline__ float dpp_qx2(float x) {  // quad_perm [2,3,0,1]
  return __int_as_float(__builtin_amdgcn_mov_dpp(__float_as_int(x), 0x4E, 0xF, 0xF, true));
}

// One backward body for time T_. Uses slot registers QV/PV/CV (loaded 4 bodies
// ago), stages F^T for T_-1 from APrev/BPrev (loaded 3 bodies ago), reloads
// this slot (QV/ASelf/BSelf/PV/CV) with data for T_-4.
#define BW_BODY(T_, QV, PV, CV, APrev, BPrev, ASelf, BSelf)                    \
{                                                                              \
  const int  t_   = (T_);                                                      \
  const long bt_  = b*TT + t_;                                                 \
  const int  tL_  = (t_ >= 4) ? (t_ - 4) : 0;                                  \
  const long btL_ = b*TT + tL_;                                                \
  float4 qN_ = *(const float4*)(Qg  + btL_*256 + 4*l);                         \
  float4 aN_ = *(const float4*)(Ag  + btL_*144 + aoff);                        \
  float4 bN_ = *(const float4*)(Bg  + btL_*48  + boff);                        \
  float  pN_ = pg[btL_*16 + j];                                                \
  float  cN_ = cug[btL_*4 + q4];                                               \
  float* FTc_ = (t_ & 1) ? FT1 : FT0;                                          \
  float* FTn_ = (t_ & 1) ? FT0 : FT1;                                          \
  /* stage F^T for t-1 (inputs landed >=3 bodies ago) */                       \
  if (l < 36) { FTn_[fta[0]]=APrev.x; FTn_[fta[1]]=APrev.y;                    \
                FTn_[fta[2]]=APrev.z; FTn_[fta[3]]=APrev.w; }                  \
  else if (l < 48) { const int kk_=l-36;                                       \
    FTn_[144+kk_]=BPrev.x; FTn_[156+kk_]=BPrev.y;                              \
    FTn_[168+kk_]=BPrev.z; FTn_[180+kk_]=BPrev.w; }                            \
  /* top-of-body LDS reads */                                                  \
  const float4* fj4_ = (const float4*)(FTc_ + j*12);                           \
  float4 f0_=fj4_[0], f1_=fj4_[1], f2_=fj4_[2];                                \
  const float4* gi4_ = (const float4*)(FTc_ + i4*12);                          \
  float4 g0_=gi4_[0], g1_=gi4_[1], g2_=gi4_[2];                                \
  const float4* vv4_ = (const float4*)vvS;                                     \
  float4 w0_=vv4_[0], w1_=vv4_[1], w2_=vv4_[2];                                \
  const float4* vr0_ = (const float4*)(Vs + (3*r+0)*12);                       \
  const float4* vr1_ = (const float4*)(Vs + (3*r+1)*12);                       \
  const float4* vr2_ = (const float4*)(Vs + (3*r+2)*12);                       \
  float4 va0_=vr0_[0], va1_=vr0_[1], va2_=vr0_[2];                             \
  float4 vb0_=vr1_[0], vb1_=vr1_[1], vb2_=vr1_[2];                             \
  float4 vc0_=vr2_[0], vc1_=vr2_[1], vc2_=vr2_[2];                             \
  float m0_ = dotf4(va0_,f0_) + dotf4(va1_,f1_) + dotf4(va2_,f2_);             \
  float m1_ = dotf4(vb0_,f0_) + dotf4(vb1_,f1_) + dotf4(vb2_,f2_);             \
  float m2_ = dotf4(vc0_,f0_) + dotf4(vc1_,f1_) + dotf4(vc2_,f2_);             \
  msh[(3*r+0)*16 + j] = m0_;                                                   \
  msh[(3*r+1)*16 + j] = m1_;                                                   \
  msh[(3*r+2)*16 + j] = m2_;                                                   \
  float qtv_ = PV + dotf4(w0_,f0_) + dotf4(w1_,f1_) + dotf4(w2_,f2_);          \
  float gk_[12] = {g0_.x,g0_.y,g0_.z,g0_.w, g1_.x,g1_.y,g1_.z,g1_.w,           \
                   g2_.x,g2_.y,g2_.z,g2_.w};                                   \
  float4 qt4_ = QV;                                                            \
  _Pragma("unroll")                                                            \
  for (int k2_ = 0; k2_ < 12; ++k2_) {                                         \
    float4 mk_ = *(const float4*)(msh + k2_*16 + c0);                          \
    qt4_.x += gk_[k2_]*mk_.x; qt4_.y += gk_[k2_]*mk_.y;                        \
    qt4_.z += gk_[k2_]*mk_.z; qt4_.w += gk_[k2_]*mk_.w;                        \
  }                                                                            \
  if (l >= 48)            *(float4*)(UxS + (i4-12)*16 + c0) = qt4_;            \
  if (q4 == 3 && i4 < 12) *(float4*)(XuS + i4*4) = qt4_;                       \
  if (l >= 12 && l < 16)  quS[l-12] = qtv_;                                    \
  float mm_[16];                                                               \
  _Pragma("unroll")                                                            \
  for (int c_ = 0; c_ < 4; ++c_) {                                             \
    float4 qq_ = *(const float4*)(UxS + c_*16 + 12);                           \
    mm_[c_*4+0]=qq_.x; mm_[c_*4+1]=qq_.y; mm_[c_*4+2]=qq_.z; mm_[c_*4+3]=qq_.w;\
  }                                                                            \
  float4 quv_ = *(const float4*)quS;                                           \
  float4 ux0_ = *(const float4*)(UxS + 0*16 + c0);                             \
  float4 ux1_ = *(const float4*)(UxS + 1*16 + c0);                             \
  float4 ux2_ = *(const float4*)(UxS + 2*16 + c0);                             \
  float4 ux3_ = *(const float4*)(UxS + 3*16 + c0);                             \
  float4 xr_ = *(const float4*)(XuS + min(i4,11)*4);                           \
  float4 xj_ = *(const float4*)(XuS + min(j,11)*4);                            \
  /* SPD 2x2-block Schur inverse of Quu */                                     \
  float rdp_ = 1.0f/(mm_[0]*mm_[5] - mm_[1]*mm_[1]);                           \
  float pi00_ = mm_[5]*rdp_, pi01_ = -mm_[1]*rdp_, pi11_ = mm_[0]*rdp_;        \
  float w00_ = pi00_*mm_[2] + pi01_*mm_[6];                                    \
  float w01_ = pi00_*mm_[3] + pi01_*mm_[7];                                    \
  float w10_ = pi01_*mm_[2] + pi11_*mm_[6];                                    \
  float w11_ = pi01_*mm_[3] + pi11_*mm_[7];                                    \
  float t00_ = mm_[10] - (mm_[2]*w00_ + mm_[6]*w10_);                          \
  float t01_ = mm_[11] - (mm_[2]*w01_ + mm_[6]*w11_);                          \
  float t11_ = mm_[15] - (mm_[3]*w01_ + mm_[7]*w11_);                          \
  float rdt_ = 1.0f/(t00_*t11_ - t01_*t01_);                                   \
  float ti00_ = t11_*rdt_, ti01_ = -t01_*rdt_, ti11_ = t00_*rdt_;              \
  float u00_ = -(w00_*ti00_ + w01_*ti01_);                                     \
  float u01_ = -(w00_*ti01_ + w01_*ti11_);                                     \
  float u10_ = -(w10_*ti00_ + w11_*ti01_);                                     \
  float u11_ = -(w10_*ti01_ + w11_*ti11_);                                     \
  float i00_ = pi00_ - (u00_*w00_ + u01_*w01_);                                \
  float i01_ = pi01_ - (u00_*w10_ + u01_*w11_);                                \
  float i11_ = pi11_ - (u10_*w10_ + u11_*w11_);                                \
  float inv_[16] = { i00_, i01_, u00_, u01_,                                   \
                     i01_, i11_, u10_, u11_,                                   \
                     u00_, u10_, ti00_, ti01_,                                 \
                     u01_, u11_, ti01_, ti11_ };                               \
  float kt0_ = -(inv_[0] *quv_.x + inv_[1] *quv_.y + inv_[2] *quv_.z + inv_[3] *quv_.w); \
  float kt1_ = -(inv_[4] *quv_.x + inv_[5] *quv_.y + inv_[6] *quv_.z + inv_[7] *quv_.w); \
  float kt2_ = -(inv_[8] *quv_.x + inv_[9] *quv_.y + inv_[10]*quv_.z + inv_[11]*quv_.w); \
  float kt3_ = -(inv_[12]*quv_.x + inv_[13]*quv_.y + inv_[14]*quv_.z + inv_[15]*quv_.w); \
  float4 kc_[4];                                                               \
  _Pragma("unroll")                                                            \
  for (int c_ = 0; c_ < 4; ++c_) {                                             \
    kc_[c_].x = -(inv_[c_*4+0]*ux0_.x + inv_[c_*4+1]*ux1_.x + inv_[c_*4+2]*ux2_.x + inv_[c_*4+3]*ux3_.x); \
    kc_[c_].y = -(inv_[c_*4+0]*ux0_.y + inv_[c_*4+1]*ux1_.y + inv_[c_*4+2]*ux2_.y + inv_[c_*4+3]*ux3_.y); \
    kc_[c_].z = -(inv_[c_*4+0]*ux0_.z + inv_[c_*4+1]*ux1_.z + inv_[c_*4+2]*ux2_.z + inv_[c_*4+3]*ux3_.z); \
    kc_[c_].w = -(inv_[c_*4+0]*ux0_.w + inv_[c_*4+1]*ux1_.w + inv_[c_*4+2]*ux2_.w + inv_[c_*4+3]*ux3_.w); \
  }                                                                            \
  if (i4 < 12) {                                                               \
    float4 vn4_;                                                               \
    vn4_.x = qt4_.x + xr_.x*kc_[0].x + xr_.y*kc_[1].x + xr_.z*kc_[2].x + xr_.w*kc_[3].x; \
    vn4_.y = qt4_.y + xr_.x*kc_[0].y + xr_.y*kc_[1].y + xr_.z*kc_[2].y + xr_.w*kc_[3].y; \
    vn4_.z = qt4_.z + xr_.x*kc_[0].z + xr_.y*kc_[1].z + xr_.z*kc_[2].z + xr_.w*kc_[3].z; \
    vn4_.w = qt4_.w + xr_.x*kc_[0].w + xr_.y*kc_[1].w + xr_.z*kc_[2].w + xr_.w*kc_[3].w; \
    if (q4 < 3) *(float4*)(Vs + i4*12 + c0) = vn4_;                            \
  }                                                                            \
  if (l < 12)                                                                  \
    vvS[l] = qtv_ + xj_.x*kt0_ + xj_.y*kt1_ + xj_.z*kt2_ + xj_.w*kt3_;         \
  float uv_ = CV + ((q4==0)?kt0_:(q4==1)?kt1_:(q4==2)?kt2_:kt3_);              \
  if (l < 4) { us_out[bt_*4 + l] = uv_; uL[t_*4 + l] = uv_; }                  \
  QV = qN_; ASelf = aN_; BSelf = bN_; PV = pN_; CV = cN_;                      \
}

__global__ __launch_bounds__(64, 1) void lqr_fused(
    const float* __restrict__ Qg, const float* __restrict__ pg,
    const float* __restrict__ Ag, const float* __restrict__ Bg,
    const float* __restrict__ cug, const float* __restrict__ xinit,
    float* __restrict__ out)
{
  __shared__ __align__(16) float lds[1376];
  float* FT0 = lds;        // [16][12] F^T buffer 0
  float* FT1 = lds + 192;  // [16][12] F^T buffer 1
  float* Vs  = lds + 384;  // [12][12]
  float* vvS = lds + 528;  // [12]
  float* msh = lds + 544;  // [12][16]
  float* UxS = lds + 736;  // [4][16]
  float* XuS = lds + 800;  // [12][4]
  float* quS = lds + 848;  // [4]
  float* uL  = lds + 864;  // [128][4]

  const int l  = threadIdx.x;
  const int j  = l & 15;
  const int r  = l >> 4;
  const int i4 = l >> 2;
  const int q4 = l & 3;
  const int c0 = q4 << 2;
  const long b = blockIdx.x;

  float* xs_out = out;
  float* us_out = out + (long)NBQ*TT*12;
  float* c_out  = out + (long)NBQ*TT*12 + (long)NBQ*TT*4;

  if (i4 < 12 && q4 < 3) *(float4*)(Vs + i4*12 + c0) = make_float4(0.f,0.f,0.f,0.f);
  if (l < 12) vvS[l] = 0.f;

  const int aoff = 4*min(l,35);
  const int boff = 4*min(max(l-36,0),11);
  int fta[4];
  #pragma unroll
  for (int e=0;e<4;++e){ int flat=4*l+e; int k=(flat*171)>>11; int n=flat-12*k; fta[e]=n*12+k; }

  // ---- prologue: load 4 slots (t=127..124), stage FT(127) ----
  const long base = b*TT;
  float4 q3v,a3v,b3v, q2v,a2v,b2v, q1v,a1v,b1v, q0v,a0v,b0v;
  float  p3v,c3v, p2v,c2v, p1v,c1v, p0v,c0vv;
  {
    long bt;
    bt = base+127; q3v=*(const float4*)(Qg+bt*256+4*l); a3v=*(const float4*)(Ag+bt*144+aoff);
                   b3v=*(const float4*)(Bg+bt*48+boff); p3v=pg[bt*16+j]; c3v=cug[bt*4+q4];
    bt = base+126; q2v=*(const float4*)(Qg+bt*256+4*l); a2v=*(const float4*)(Ag+bt*144+aoff);
                   b2v=*(const float4*)(Bg+bt*48+boff); p2v=pg[bt*16+j]; c2v=cug[bt*4+q4];
    bt = base+125; q1v=*(const float4*)(Qg+bt*256+4*l); a1v=*(const float4*)(Ag+bt*144+aoff);
                   b1v=*(const float4*)(Bg+bt*48+boff); p1v=pg[bt*16+j]; c1v=cug[bt*4+q4];
    bt = base+124; q0v=*(const float4*)(Qg+bt*256+4*l); a0v=*(const float4*)(Ag+bt*144+aoff);
                   b0v=*(const float4*)(Bg+bt*48+boff); p0v=pg[bt*16+j]; c0vv=cug[bt*4+q4];
  }
  // stage FT for t=127 into buf1 (127&1==1)
  if (l < 36) {
    FT1[fta[0]]=a3v.x; FT1[fta[1]]=a3v.y; FT1[fta[2]]=a3v.z; FT1[fta[3]]=a3v.w;
  } else if (l < 48) {
    const int kk=l-36;
    FT1[144+kk]=b3v.x; FT1[156+kk]=b3v.y; FT1[168+kk]=b3v.z; FT1[180+kk]=b3v.w;
  }

  // ---- backward scan, unrolled x4 with slot rotation ----
  #pragma unroll 1
  for (int tb = TT-1; tb >= 3; tb -= 4) {
    BW_BODY(tb,   q3v, p3v, c3v,  a2v, b2v,  a3v, b3v)
    BW_BODY(tb-1, q2v, p2v, c2v,  a1v, b1v,  a2v, b2v)
    BW_BODY(tb-2, q1v, p1v, c1v,  a0v, b0v,  a1v, b1v)
    BW_BODY(tb-3, q0v, p0v, c0vv, a3v, b3v,  a0v, b0v)
  }

  // ---------------- forward rollout + cost ----------------
  const int i4c = min(i4, 11);
  const int sl0 = (c0+0)<<2, sl1 = (c0+1)<<2, sl2 = (c0+2)<<2, sl3 = (c0+3)<<2;
  float s = xinit[b*12 + i4c];
  float cacc = 0.f;

  const long bt0 = base;
  // 3-deep prefetch: A(t), B(t+1), C(t+2)
  float4 qfA = *(const float4*)(Qg + bt0*256 + 4*l);
  float4 ffA = (q4 < 3) ? *(const float4*)(Ag + bt0*144 + i4c*12 + c0)
                        : *(const float4*)(Bg + bt0*48  + i4c*4);
  float  pfA = pg[bt0*16 + i4];
  float4 qfB = *(const float4*)(Qg + (bt0+1)*256 + 4*l);
  float4 ffB = (q4 < 3) ? *(const float4*)(Ag + (bt0+1)*144 + i4c*12 + c0)
                        : *(const float4*)(Bg + (bt0+1)*48  + i4c*4);
  float  pfB = pg[(bt0+1)*16 + i4];
  float4 qfC = *(const float4*)(Qg + (bt0+2)*256 + 4*l);
  float4 ffC = (q4 < 3) ? *(const float4*)(Ag + (bt0+2)*144 + i4c*12 + c0)
                        : *(const float4*)(Bg + (bt0+2)*48  + i4c*4);
  float  pfC = pg[(bt0+2)*16 + i4];

  #pragma unroll 1
  for (int t = 0; t < TT; ++t) {
    const long btp = bt0 + min(t+3, TT-1);
    float4 qfD = *(const float4*)(Qg + btp*256 + 4*l);
    float4 ffD = (q4 < 3) ? *(const float4*)(Ag + btp*144 + i4c*12 + c0)
                          : *(const float4*)(Bg + btp*48  + i4c*4);
    float  pfD = pg[btp*16 + i4];

    float4 u4 = *(const float4*)(uL + t*4);

    float4 xg;
    xg.x = __shfl(s, sl0, 64); xg.y = __shfl(s, sl1, 64);
    xg.z = __shfl(s, sl2, 64); xg.w = __shfl(s, sl3, 64);
    float4 xuq = (q4 < 3) ? xg : u4;
    float xui = (i4 < 12) ? s
              : (i4 == 12) ? u4.x : (i4 == 13) ? u4.y : (i4 == 14) ? u4.z : u4.w;

    if (q4 == 0 && i4 < 12) xs_out[(bt0+t)*12 + i4] = s;

    cacc += 0.5f * xui * dotf4(qfA, xuq);
    if (q4 == 0) cacc += xui * pfA;

    float zx = dotf4(ffA, xuq);
    zx += dpp_qx1(zx);
    zx += dpp_qx2(zx);
    s = zx;

    qfA = qfB; ffA = ffB; pfA = pfB;
    qfB = qfC; ffB = ffC; pfB = pfC;
    qfC = qfD; ffC = ffD; pfC = pfD;
  }

  cacc += __shfl_xor(cacc, 32, 64);
  cacc += __shfl_xor(cacc, 16, 64);
  cacc += __shfl_xor(cacc, 8, 64);
  cacc += __shfl_xor(cacc, 4, 64);
  cacc += dpp_qx2(cacc);
  cacc += dpp_qx1(cacc);
  if (l == 0) c_out[b] = cacc;
}

extern "C" void kernel_launch(void* const* d_in, const int* in_sizes, int n_in,
                              void* d_out, int out_size, void* d_ws, size_t ws_size,
                              hipStream_t stream) {
  const float* xinit = (const float*)d_in[0];
  // d_in[1] = current_x (unused by reference), d_in[7] = time (unused)
  const float* cu = (const float*)d_in[2];
  const float* Q  = (const float*)d_in[3];
  const float* p  = (const float*)d_in[4];
  const float* A  = (const float*)d_in[5];
  const float* Bm = (const float*)d_in[6];
  float* out = (float*)d_out;

  lqr_fused<<<dim3(NBQ), dim3(64), 0, stream>>>(Q, p, A, Bm, cu, xinit, out);
}

// Round 6
// 383.116 us; speedup vs baseline: 1.2178x; 1.0395x over previous
//
#include <hip/hip_runtime.h>

// NLQR: NB=1024, T=128, NS=12, NC=4, N=16.
// Round 6 = Round 5 (DS-pipe decongestion) + OOB fix in the strided F load:
// A-part lanes cover only 3 elements; the 4th strided read at +144 ran past
// the end of A for b=1023's prologue -> GPU fault. 4th offset now clamped.
// Design (unchanged from R5):
//   Qt = Q + F^T V F; qt = p + F^T v; kt = -Quu^{-1} qu; K = -Quu^{-1} Qux;
//   Vn = Qxx + Qxu K; vn = qx + Qxu kt; u = cu + kt.
//  - qt-step lane layout (cb = l>>4, i = l&15): f-read serves both steps
//  - quad-distributed LDS reads + DPP quad_perm broadcasts for V rows, vv,
//    msh, Quu, Qux -> ~27 DS ops/iter (was ~53 in R4)
//  - 4-deep global prefetch (validated R4), zero barriers, 1 wave/block

#define NBQ 1024
#define TT  128

__device__ __forceinline__ float dotf4(float4 a, float4 b) {
  return a.x*b.x + a.y*b.y + a.z*b.z + a.w*b.w;
}
__device__ __forceinline__ float dpp_qx1(float x) {  // quad_perm [1,0,3,2]
  return __int_as_float(__builtin_amdgcn_mov_dpp(__float_as_int(x), 0xB1, 0xF, 0xF, true));
}
__device__ __forceinline__ float dpp_qx2(float x) {  // quad_perm [2,3,0,1]
  return __int_as_float(__builtin_amdgcn_mov_dpp(__float_as_int(x), 0x4E, 0xF, 0xF, true));
}
template<int Q> __device__ __forceinline__ float4 bcast4(float4 v) {
  // broadcast quad-lane Q's float4 to all lanes of the quad (pure VALU)
  float4 r;
  r.x = __int_as_float(__builtin_amdgcn_mov_dpp(__float_as_int(v.x), Q*0x55, 0xF, 0xF, true));
  r.y = __int_as_float(__builtin_amdgcn_mov_dpp(__float_as_int(v.y), Q*0x55, 0xF, 0xF, true));
  r.z = __int_as_float(__builtin_amdgcn_mov_dpp(__float_as_int(v.z), Q*0x55, 0xF, 0xF, true));
  r.w = __int_as_float(__builtin_amdgcn_mov_dpp(__float_as_int(v.w), Q*0x55, 0xF, 0xF, true));
  return r;
}

#define MKS(K, O, MY)  { float4 mk_ = bcast4<O>(MY);                           \
  qt4_.x += gk_[K]*mk_.x; qt4_.y += gk_[K]*mk_.y;                              \
  qt4_.z += gk_[K]*mk_.z; qt4_.w += gk_[K]*mk_.w; }

// One backward body at time T_. Slot regs QV/PV/CV + F-scalars loaded 4 bodies
// ago; stages F^T for T_-1 from prev slot's F-scalars (loaded 3 bodies ago);
// reloads self slot with T_-4 data.
#define BW_BODY(T_, QV, PV, CV, P0,P1,P2,P3, S0,S1,S2,S3)                      \
{                                                                              \
  const int  t_   = (T_);                                                      \
  const long bt_  = b*TT + t_;                                                 \
  const long btL_ = b*TT + ((t_ >= 4) ? (t_ - 4) : 0);                         \
  float4 qN_ = *(const float4*)(Qg + btL_*256 + qoff);                         \
  const float* fpL_ = lt48 ? (Ag + btL_*144 + l) : (Bg + btL_*48 + bm_);       \
  float fN0_ = fpL_[0], fN1_ = fpL_[fstr_], fN2_ = fpL_[2*fstr_], fN3_ = fpL_[foff3];  \
  float  pN_ = pg[btL_*16 + j];                                                \
  float  cN_ = cug[btL_*4 + q4];                                               \
  float* FTc_ = (t_ & 1) ? FT1 : FT0;                                          \
  float* FTn_ = (t_ & 1) ? FT0 : FT1;                                          \
  /* stage F^T for t_-1 (write2-mergeable static offsets) */                   \
  if (lt48)      { FTn_[ba] = P0; FTn_[ba+4] = P1; FTn_[ba+8] = P2; }          \
  else if (lt60) { FTn_[bb] = P0; FTn_[bb+3] = P1; FTn_[bb+6] = P2; FTn_[bb+9] = P3; } \
  /* reads: f = F col (l&15) (serves m-step AND qt-step), own V row, own vv */ \
  const float4* fj4_ = (const float4*)(FTc_ + j*12);                           \
  float4 f0_=fj4_[0], f1_=fj4_[1], f2_=fj4_[2];                                \
  const float4* vrow_ = (const float4*)(Vs + (3*r + dmin)*12);                 \
  float4 mv0_=vrow_[0], mv1_=vrow_[1], mv2_=vrow_[2];                          \
  float4 mw_ = *(const float4*)(vvS + 4*dmin);                                 \
  /* m rows via quad broadcast of V rows */                                    \
  float m0_, m1_, m2_;                                                         \
  { float4 r0_=bcast4<0>(mv0_), r1_=bcast4<0>(mv1_), r2_=bcast4<0>(mv2_);      \
    m0_ = dotf4(r0_,f0_)+dotf4(r1_,f1_)+dotf4(r2_,f2_); }                      \
  { float4 r0_=bcast4<1>(mv0_), r1_=bcast4<1>(mv1_), r2_=bcast4<1>(mv2_);      \
    m1_ = dotf4(r0_,f0_)+dotf4(r1_,f1_)+dotf4(r2_,f2_); }                      \
  { float4 r0_=bcast4<2>(mv0_), r1_=bcast4<2>(mv1_), r2_=bcast4<2>(mv2_);      \
    m2_ = dotf4(r0_,f0_)+dotf4(r1_,f1_)+dotf4(r2_,f2_); }                      \
  msh[(3*r+0)*16 + j] = m0_;                                                   \
  msh[(3*r+1)*16 + j] = m1_;                                                   \
  msh[(3*r+2)*16 + j] = m2_;                                                   \
  /* qtv via vv quad broadcast (fills msh write->read latency) */              \
  float qtv_;                                                                  \
  { float4 w0_=bcast4<0>(mw_), w1_=bcast4<1>(mw_), w2_=bcast4<2>(mw_);         \
    qtv_ = PV + dotf4(w0_,f0_)+dotf4(w1_,f1_)+dotf4(w2_,f2_); }                \
  /* qt tile: lane (cb, i=l&15) computes Qt[i][4cb..4cb+3] */                  \
  float gk_[12] = {f0_.x,f0_.y,f0_.z,f0_.w, f1_.x,f1_.y,f1_.z,f1_.w,           \
                   f2_.x,f2_.y,f2_.z,f2_.w};                                   \
  float4 mys0_ = *(const float4*)(msh + (3*q4+0)*16 + cb4);                    \
  float4 mys1_ = *(const float4*)(msh + (3*q4+1)*16 + cb4);                    \
  float4 mys2_ = *(const float4*)(msh + (3*q4+2)*16 + cb4);                    \
  float4 qt4_ = QV;                                                            \
  MKS(0,0,mys0_) MKS(1,0,mys1_) MKS(2,0,mys2_)                                 \
  MKS(3,1,mys0_) MKS(4,1,mys1_) MKS(5,1,mys2_)                                 \
  MKS(6,2,mys0_) MKS(7,2,mys1_) MKS(8,2,mys2_)                                 \
  MKS(9,3,mys0_) MKS(10,3,mys1_) MKS(11,3,mys2_)                               \
  /* publish Qux|Quu rows, Qxu, qu */                                          \
  if (j >= 12)           *(float4*)(UxS + (j-12)*16 + cb4) = qt4_;             \
  if (cb == 3 && j < 12) *(float4*)(XuS + j*4) = qt4_;                         \
  if (l >= 12 && l < 16) quS[l-12] = qtv_;                                     \
  /* quad-distributed dependent reads */                                       \
  float4 myquu_ = *(const float4*)(UxS + q4*16 + 12);                          \
  float4 myux_  = *(const float4*)(UxS + q4*16 + cb4);                         \
  float4 quv_   = *(const float4*)quS;                                         \
  float4 xr_    = *(const float4*)(XuS + jc*4);                                \
  float mm_[16];                                                               \
  { float4 t0_=bcast4<0>(myquu_); mm_[0]=t0_.x; mm_[1]=t0_.y; mm_[2]=t0_.z; mm_[3]=t0_.w; \
    float4 t1_=bcast4<1>(myquu_); mm_[4]=t1_.x; mm_[5]=t1_.y; mm_[6]=t1_.z; mm_[7]=t1_.w; \
    float4 t2_=bcast4<2>(myquu_); mm_[8]=t2_.x; mm_[9]=t2_.y; mm_[10]=t2_.z; mm_[11]=t2_.w; \
    float4 t3_=bcast4<3>(myquu_); mm_[12]=t3_.x; mm_[13]=t3_.y; mm_[14]=t3_.z; mm_[15]=t3_.w; } \
  float4 ux0_=bcast4<0>(myux_), ux1_=bcast4<1>(myux_),                         \
         ux2_=bcast4<2>(myux_), ux3_=bcast4<3>(myux_);                         \
  /* SPD 2x2-block Schur inverse of Quu */                                     \
  float rdp_ = 1.0f/(mm_[0]*mm_[5] - mm_[1]*mm_[1]);                           \
  float pi00_ = mm_[5]*rdp_, pi01_ = -mm_[1]*rdp_, pi11_ = mm_[0]*rdp_;        \
  float w00_ = pi00_*mm_[2] + pi01_*mm_[6];                                    \
  float w01_ = pi00_*mm_[3] + pi01_*mm_[7];                                    \
  float w10_ = pi01_*mm_[2] + pi11_*mm_[6];                                    \
  float w11_ = pi01_*mm_[3] + pi11_*mm_[7];                                    \
  float t00_ = mm_[10] - (mm_[2]*w00_ + mm_[6]*w10_);                          \
  float t01_ = mm_[11] - (mm_[2]*w01_ + mm_[6]*w11_);                          \
  float t11_ = mm_[15] - (mm_[3]*w01_ + mm_[7]*w11_);                          \
  float rdt_ = 1.0f/(t00_*t11_ - t01_*t01_);                                   \
  float ti00_ = t11_*rdt_, ti01_ = -t01_*rdt_, ti11_ = t00_*rdt_;              \
  float u00_ = -(w00_*ti00_ + w01_*ti01_);                                     \
  float u01_ = -(w00_*ti01_ + w01_*ti11_);                                     \
  float u10_ = -(w10_*ti00_ + w11_*ti01_);                                     \
  float u11_ = -(w10_*ti01_ + w11_*ti11_);                                     \
  float i00_ = pi00_ - (u00_*w00_ + u01_*w01_);                                \
  float i01_ = pi01_ - (u00_*w10_ + u01_*w11_);                                \
  float i11_ = pi11_ - (u10_*w10_ + u11_*w11_);                                \
  float inv_[16] = { i00_, i01_, u00_, u01_,                                   \
                     i01_, i11_, u10_, u11_,                                   \
                     u00_, u10_, ti00_, ti01_,                                 \
                     u01_, u11_, ti01_, ti11_ };                               \
  float kt0_ = -(inv_[0] *quv_.x + inv_[1] *quv_.y + inv_[2] *quv_.z + inv_[3] *quv_.w); \
  float kt1_ = -(inv_[4] *quv_.x + inv_[5] *quv_.y + inv_[6] *quv_.z + inv_[7] *quv_.w); \
  float kt2_ = -(inv_[8] *quv_.x + inv_[9] *quv_.y + inv_[10]*quv_.z + inv_[11]*quv_.w); \
  float kt3_ = -(inv_[12]*quv_.x + inv_[13]*quv_.y + inv_[14]*quv_.z + inv_[15]*quv_.w); \
  float4 kc_[4];                                                               \
  _Pragma("unroll")                                                            \
  for (int c_ = 0; c_ < 4; ++c_) {                                             \
    kc_[c_].x = -(inv_[c_*4+0]*ux0_.x + inv_[c_*4+1]*ux1_.x + inv_[c_*4+2]*ux2_.x + inv_[c_*4+3]*ux3_.x); \
    kc_[c_].y = -(inv_[c_*4+0]*ux0_.y + inv_[c_*4+1]*ux1_.y + inv_[c_*4+2]*ux2_.y + inv_[c_*4+3]*ux3_.y); \
    kc_[c_].z = -(inv_[c_*4+0]*ux0_.z + inv_[c_*4+1]*ux1_.z + inv_[c_*4+2]*ux2_.z + inv_[c_*4+3]*ux3_.z); \
    kc_[c_].w = -(inv_[c_*4+0]*ux0_.w + inv_[c_*4+1]*ux1_.w + inv_[c_*4+2]*ux2_.w + inv_[c_*4+3]*ux3_.w); \
  }                                                                            \
  if (j < 12) {                                                                \
    float4 vn4_;                                                               \
    vn4_.x = qt4_.x + xr_.x*kc_[0].x + xr_.y*kc_[1].x + xr_.z*kc_[2].x + xr_.w*kc_[3].x; \
    vn4_.y = qt4_.y + xr_.x*kc_[0].y + xr_.y*kc_[1].y + xr_.z*kc_[2].y + xr_.w*kc_[3].y; \
    vn4_.z = qt4_.z + xr_.x*kc_[0].z + xr_.y*kc_[1].z + xr_.z*kc_[2].z + xr_.w*kc_[3].z; \
    vn4_.w = qt4_.w + xr_.x*kc_[0].w + xr_.y*kc_[1].w + xr_.z*kc_[2].w + xr_.w*kc_[3].w; \
    if (cb < 3) *(float4*)(Vs + j*12 + cb4) = vn4_;                            \
  }                                                                            \
  if (l < 12)                                                                  \
    vvS[l] = qtv_ + xr_.x*kt0_ + xr_.y*kt1_ + xr_.z*kt2_ + xr_.w*kt3_;         \
  float uv_ = CV + ((q4==0)?kt0_:(q4==1)?kt1_:(q4==2)?kt2_:kt3_);              \
  if (l < 4) { us_out[bt_*4 + l] = uv_; uL[t_*4 + l] = uv_; }                  \
  QV = qN_; S0 = fN0_; S1 = fN1_; S2 = fN2_; S3 = fN3_; PV = pN_; CV = cN_;    \
}

__global__ __launch_bounds__(64, 1) void lqr_fused(
    const float* __restrict__ Qg, const float* __restrict__ pg,
    const float* __restrict__ Ag, const float* __restrict__ Bg,
    const float* __restrict__ cug, const float* __restrict__ xinit,
    float* __restrict__ out)
{
  __shared__ __align__(16) float lds[1376];
  float* FT0 = lds;        // [16][12] F^T buffer 0  (FT[n][k] = F[k][n])
  float* FT1 = lds + 192;  // [16][12] F^T buffer 1
  float* Vs  = lds + 384;  // [12][12]
  float* vvS = lds + 528;  // [12]
  float* msh = lds + 544;  // [12][16]
  float* UxS = lds + 736;  // [4][16]
  float* XuS = lds + 800;  // [12][4]
  float* quS = lds + 848;  // [4]
  float* uL  = lds + 864;  // [128][4]

  const int l    = threadIdx.x;
  const int j    = l & 15;         // m-step col / qt-step row i (f==g trick)
  const int r    = l >> 4;         // m-step row group
  const int q4   = l & 3;
  const int cb   = l >> 4;         // qt-step column block
  const int cb4  = cb << 2;
  const int dmin = (q4 < 2) ? q4 : 2;
  const int jc   = (j < 12) ? j : 11;
  const long b   = blockIdx.x;
  const bool lt48 = (l < 48);
  const bool lt60 = (l < 60);
  const int  bm_  = lt48 ? 0 : ((l - 48) % 12);
  const int  fstr_ = lt48 ? 48 : 12;
  const int  foff3 = lt48 ? 96 : 36;   // OOB fix: A lanes re-read 2*48 (unused)
  const int  ba = (l % 12) * 12 + l / 12;                 // A-part FT base
  const int  bb = 144 + ((l - 48) & 3) * 12 + ((l - 48) >> 2);  // B-part FT base
  const int  qoff = j * 16 + cb4;                          // Q[i][4cb..]

  float* xs_out = out;
  float* us_out = out + (long)NBQ*TT*12;
  float* c_out  = out + (long)NBQ*TT*12 + (long)NBQ*TT*4;

  if (j < 12 && cb < 3) *(float4*)(Vs + j*12 + cb4) = make_float4(0.f,0.f,0.f,0.f);
  if (l < 12) vvS[l] = 0.f;

  // ---- prologue: 4 slots (t = 127..124), stage FT(127) into buf1 ----
  const long base = b*TT;
  float4 q3v,q2v,q1v,q0v;
  float  p3v,c3v,p2v,c2v,p1v,c1v,p0v,c0v;
  float  f3a,f3b,f3c,f3d, f2a,f2b,f2c,f2d, f1a,f1b,f1c,f1d, f0a,f0b,f0c,f0d;
  {
    long bt;
    bt = base+127; q3v=*(const float4*)(Qg+bt*256+qoff); p3v=pg[bt*16+j]; c3v=cug[bt*4+q4];
    { const float* fp = lt48 ? (Ag+bt*144+l) : (Bg+bt*48+bm_);
      f3a=fp[0]; f3b=fp[fstr_]; f3c=fp[2*fstr_]; f3d=fp[foff3]; }
    bt = base+126; q2v=*(const float4*)(Qg+bt*256+qoff); p2v=pg[bt*16+j]; c2v=cug[bt*4+q4];
    { const float* fp = lt48 ? (Ag+bt*144+l) : (Bg+bt*48+bm_);
      f2a=fp[0]; f2b=fp[fstr_]; f2c=fp[2*fstr_]; f2d=fp[foff3]; }
    bt = base+125; q1v=*(const float4*)(Qg+bt*256+qoff); p1v=pg[bt*16+j]; c1v=cug[bt*4+q4];
    { const float* fp = lt48 ? (Ag+bt*144+l) : (Bg+bt*48+bm_);
      f1a=fp[0]; f1b=fp[fstr_]; f1c=fp[2*fstr_]; f1d=fp[foff3]; }
    bt = base+124; q0v=*(const float4*)(Qg+bt*256+qoff); p0v=pg[bt*16+j]; c0v=cug[bt*4+q4];
    { const float* fp = lt48 ? (Ag+bt*144+l) : (Bg+bt*48+bm_);
      f0a=fp[0]; f0b=fp[fstr_]; f0c=fp[2*fstr_]; f0d=fp[foff3]; }
  }
  if (lt48)      { FT1[ba] = f3a; FT1[ba+4] = f3b; FT1[ba+8] = f3c; }
  else if (lt60) { FT1[bb] = f3a; FT1[bb+3] = f3b; FT1[bb+6] = f3c; FT1[bb+9] = f3d; }

  // ---- backward scan, unrolled x4 with slot rotation ----
  #pragma unroll 1
  for (int tb = TT-1; tb >= 3; tb -= 4) {
    BW_BODY(tb,   q3v, p3v, c3v,  f2a,f2b,f2c,f2d,  f3a,f3b,f3c,f3d)
    BW_BODY(tb-1, q2v, p2v, c2v,  f1a,f1b,f1c,f1d,  f2a,f2b,f2c,f2d)
    BW_BODY(tb-2, q1v, p1v, c1v,  f0a,f0b,f0c,f0d,  f1a,f1b,f1c,f1d)
    BW_BODY(tb-3, q0v, p0v, c0v,  f3a,f3b,f3c,f3d,  f0a,f0b,f0c,f0d)
  }

  // ---------------- forward rollout + cost ----------------
  const int i4  = l >> 2;
  const int c0f = q4 << 2;
  const int i4c = (i4 < 12) ? i4 : 11;
  const int sl0 = (c0f+0)<<2, sl1 = (c0f+1)<<2, sl2 = (c0f+2)<<2, sl3 = (c0f+3)<<2;
  float s = xinit[b*12 + i4c];
  float cacc = 0.f;

  const long bt0 = base;
  float4 qfA = *(const float4*)(Qg + bt0*256 + 4*l);
  float4 ffA = (q4 < 3) ? *(const float4*)(Ag + bt0*144 + i4c*12 + c0f)
                        : *(const float4*)(Bg + bt0*48  + i4c*4);
  float  pfA = pg[bt0*16 + i4];
  float4 qfB = *(const float4*)(Qg + (bt0+1)*256 + 4*l);
  float4 ffB = (q4 < 3) ? *(const float4*)(Ag + (bt0+1)*144 + i4c*12 + c0f)
                        : *(const float4*)(Bg + (bt0+1)*48  + i4c*4);
  float  pfB = pg[(bt0+1)*16 + i4];
  float4 qfC = *(const float4*)(Qg + (bt0+2)*256 + 4*l);
  float4 ffC = (q4 < 3) ? *(const float4*)(Ag + (bt0+2)*144 + i4c*12 + c0f)
                        : *(const float4*)(Bg + (bt0+2)*48  + i4c*4);
  float  pfC = pg[(bt0+2)*16 + i4];

  #pragma unroll 1
  for (int t = 0; t < TT; ++t) {
    const long btp = bt0 + ((t+3 < TT-1) ? t+3 : TT-1);
    float4 qfD = *(const float4*)(Qg + btp*256 + 4*l);
    float4 ffD = (q4 < 3) ? *(const float4*)(Ag + btp*144 + i4c*12 + c0f)
                          : *(const float4*)(Bg + btp*48  + i4c*4);
    float  pfD = pg[btp*16 + i4];

    float4 u4 = *(const float4*)(uL + t*4);

    float4 xg;
    xg.x = __shfl(s, sl0, 64); xg.y = __shfl(s, sl1, 64);
    xg.z = __shfl(s, sl2, 64); xg.w = __shfl(s, sl3, 64);
    float4 xuq = (q4 < 3) ? xg : u4;
    float xui = (i4 < 12) ? s
              : (i4 == 12) ? u4.x : (i4 == 13) ? u4.y : (i4 == 14) ? u4.z : u4.w;

    if (q4 == 0 && i4 < 12) xs_out[(bt0+t)*12 + i4] = s;

    cacc += 0.5f * xui * dotf4(qfA, xuq);
    if (q4 == 0) cacc += xui * pfA;

    float zx = dotf4(ffA, xuq);
    zx += dpp_qx1(zx);
    zx += dpp_qx2(zx);
    s = zx;

    qfA = qfB; ffA = ffB; pfA = pfB;
    qfB = qfC; ffB = ffC; pfB = pfC;
    qfC = qfD; ffC = ffD; pfC = pfD;
  }

  cacc += __shfl_xor(cacc, 32, 64);
  cacc += __shfl_xor(cacc, 16, 64);
  cacc += __shfl_xor(cacc, 8, 64);
  cacc += __shfl_xor(cacc, 4, 64);
  cacc += dpp_qx2(cacc);
  cacc += dpp_qx1(cacc);
  if (l == 0) c_out[b] = cacc;
}

extern "C" void kernel_launch(void* const* d_in, const int* in_sizes, int n_in,
                              void* d_out, int out_size, void* d_ws, size_t ws_size,
                              hipStream_t stream) {
  const float* xinit = (const float*)d_in[0];
  // d_in[1] = current_x (unused by reference), d_in[7] = time (unused)
  const float* cu = (const float*)d_in[2];
  const float* Q  = (const float*)d_in[3];
  const float* p  = (const float*)d_in[4];
  const float* A  = (const float*)d_in[5];
  const float* Bm = (const float*)d_in[6];
  float* out = (float*)d_out;

  lqr_fused<<<dim3(NBQ), dim3(64), 0, stream>>>(Q, p, A, Bm, cu, xinit, out);
}